// Round 6
// baseline (1064.460 us; speedup 1.0000x reference)
//
#include <hip/hip_runtime.h>
#include <hip/hip_cooperative_groups.h>
#include <cstdint>

namespace cg = cooperative_groups;

// Fisher-Kolmogorov explicit Euler, B=2, 128^3, up to 30 masked micro-steps
// (delta_t_days = randint(0,4) -> d <= 3 -> steps <= 30).
// Round-15: persistent cooperative kernel, retried with SAFE sizing + fallback.
//  R14 counters falsified the byte model: fk_triple moved 98MB/launch at only
//  2.3 TB/s (29% fabric), VALUBusy 9-20% -> latency/serialization-bound, not
//  byte-bound. The only remaining lever is killing the per-launch volume
//  re-read/re-write: keep u (u[8]) and packed (D,rho) bf16 (pk[8]) in
//  REGISTERS for all 30 steps; per step only tile surfaces move (~12MB/step
//  grid-wide vs ~100MB/launch now).
//  R13's failure signature (out == memset zeros, absmax exactly 1.0) says the
//  cooperative LAUNCH was rejected (512 blocks needed exactly 2 blocks/CU),
//  not that the algorithm raced. Fixes here:
//   - 256 blocks x 512 threads: 1 block/CU -> occupancy validation cannot
//     reject; all blocks trivially co-resident.
//   - launch return code checked; on ANY error fall back to the verified
//     R12 multi-launch kernel (234us, passed) -> downside capped.
//  Exchange protocol (unchanged from R13 audit): faces of state g parity-
//  buffered by g&1; write faces -> grid.sync -> read rims. One sync/step is
//  race-free: iter g+2's writes to buf[g&1] are separated from iter g's reads
//  of buf[g&1] by iter g+1's grid.sync.

constexpr int NX = 128, NY = 128, NZ = 128;
constexpr int PLANE = NX * NY;            // 16384
constexpr int VOL   = NZ * PLANE;         // 2,097,152
constexpr int TOTAL = 2 * VOL;            // 4,194,304
constexpr float DT  = 0.1f;               // MICRO_DT
constexpr int NSTEP = 30;

// ---- cooperative geometry: 256 blocks (1/CU), tile 8z x 16y x full-x ----
constexpr int CTZ = 8, CTY = 16;
constexpr int CBLOCKS  = 2 * (NZ / CTZ) * (NY / CTY);  // 2*16*8 = 256
constexpr int CTHREADS = 512;                          // 16 rows x 32 f4-lanes

// ---- fallback (R12) geometry ----
constexpr int TY = 8, TZ = 4;
constexpr int S1Z = TZ + 4, S1Y = TY + 4;
constexpr int S2Z = TZ + 2, S2Y = TY + 2;
constexpr int FBLOCKS = 2 * (NZ / TZ) * (NY / TY);     // 1024
constexpr int MAX_TRIPLES = 10;

__device__ __forceinline__ float4 ld4(const float* p) { return *(const float4*)p; }

__device__ __forceinline__ uint32_t f2bf(float f) {
    uint32_t u = __float_as_uint(f);
    u += 0x7fffu + ((u >> 16) & 1u);      // round-to-nearest-even
    return u >> 16;
}
__device__ __forceinline__ float bf_lo(uint32_t p) { return __uint_as_float(p << 16); }
__device__ __forceinline__ float bf_hi(uint32_t p) { return __uint_as_float(p & 0xffff0000u); }
__device__ __forceinline__ float clip01(float v) { return fminf(fmaxf(v, 0.0f), 1.0f); }

__device__ __forceinline__ float4 fkstep(float dt, float4 c, float xm, float xp,
                                         float4 ym, float4 yp,
                                         float4 zm, float4 zp,
                                         float4 Dv, float4 Rv) {
    float4 o;
    o.x = fmaf(dt, fmaf(Dv.x, (xm + c.y) + (ym.x + yp.x) + (zm.x + zp.x) - 6.0f * c.x,
                        Rv.x * c.x * (1.0f - c.x)), c.x);
    o.y = fmaf(dt, fmaf(Dv.y, (c.x + c.z) + (ym.y + yp.y) + (zm.y + zp.y) - 6.0f * c.y,
                        Rv.y * c.y * (1.0f - c.y)), c.y);
    o.z = fmaf(dt, fmaf(Dv.z, (c.y + c.w) + (ym.z + yp.z) + (zm.z + zp.z) - 6.0f * c.z,
                        Rv.z * c.z * (1.0f - c.z)), c.z);
    o.w = fmaf(dt, fmaf(Dv.w, (c.z + xp) + (ym.w + yp.w) + (zm.w + zp.w) - 6.0f * c.w,
                        Rv.w * c.w * (1.0f - c.w)), c.w);
    return o;
}

__device__ __forceinline__ float4 unpackD(uint4 p) {
    return make_float4(bf_lo(p.x), bf_lo(p.y), bf_lo(p.z), bf_lo(p.w));
}
__device__ __forceinline__ float4 unpackR(uint4 p) {
    return make_float4(bf_hi(p.x), bf_hi(p.y), bf_hi(p.z), bf_hi(p.w));
}

// ===================== cooperative persistent kernel =====================
__global__ __launch_bounds__(CTHREADS, 2)   // VGPR cap 256; 1 block/CU safe
void fk_persist(const float* __restrict__ u0, const float* __restrict__ Dm,
                const float* __restrict__ Rm, const int* __restrict__ dtd,
                float* __restrict__ out, float* __restrict__ buf0,
                float* __restrict__ buf1)
{
    cg::grid_group grid = cg::this_grid();

    const int bid = blockIdx.x;
    const int b   = bid >> 7;                       // batch item
    const int zb  = (bid >> 3) & 15;                // z tile 0..15
    const int yt  = bid & 7;                        // y tile 0..7
    const int z0  = zb * CTZ, y0 = yt * CTY;
    const int tid = threadIdx.x;
    const int xq  = tid & 31;                       // f4 lane in row
    const int yi  = tid >> 5;                       // row 0..15
    const int y   = y0 + yi;
    const int baseb = b << 21;
    const int col = baseb + y * NX + (xq << 2);
    const float4 zero = make_float4(0.f, 0.f, 0.f, 0.f);

    int d = dtd[b]; d = d < 0 ? 0 : (d > 3 ? 3 : d);
    const int steps = d * 10;

    // ---- Prologue: own column (8 z-cells) into registers, persist ----
    float4 u[CTZ];
    uint4  pk[CTZ];
    #pragma unroll
    for (int k = 0; k < CTZ; ++k) {
        const int idx = col + (z0 + k) * PLANE;
        u[k] = ld4(u0 + idx);
        const float4 Dv = ld4(Dm + idx);
        const float4 Rv = ld4(Rm + idx);
        pk[k].x = f2bf(Dv.x) | (f2bf(Rv.x) << 16);
        pk[k].y = f2bf(Dv.y) | (f2bf(Rv.y) << 16);
        pk[k].z = f2bf(Dv.z) | (f2bf(Rv.z) << 16);
        pk[k].w = f2bf(Dv.w) | (f2bf(Rv.w) << 16);
    }
    if (steps == 0) {                               // d==0: out = clip(u0)
        #pragma unroll
        for (int k = 0; k < CTZ; ++k) {
            const int idx = col + (z0 + k) * PLANE;
            float4 o;
            o.x = clip01(u[k].x); o.y = clip01(u[k].y);
            o.z = clip01(u[k].z); o.w = clip01(u[k].w);
            *(float4*)(out + idx) = o;
        }
    }

    __shared__ float sU[CTZ][CTY][NX];              // 64 KiB tile stage

    // Every block executes exactly NSTEP grid.sync()s (no early return).
    for (int g = 0; g < NSTEP; ++g) {
        float* __restrict__ fb = (g & 1) ? buf1 : buf0;
        const bool act = (g < steps);               // block-uniform

        __syncthreads();                            // LDS reuse guard

        if (act) {
            // z faces (k=0, k=7) for all rows; y-edge rows publish k=1..6
            *(float4*)(fb + col + (z0    ) * PLANE) = u[0];
            *(float4*)(fb + col + (z0 + 7) * PLANE) = u[7];
            if (yi == 0 || yi == CTY - 1) {
                #pragma unroll
                for (int k = 1; k < CTZ - 1; ++k)
                    *(float4*)(fb + col + (z0 + k) * PLANE) = u[k];
            }
            #pragma unroll
            for (int k = 0; k < CTZ; ++k)
                *(float4*)&sU[k][yi][xq << 2] = u[k];
        }

        grid.sync();                                // faces + LDS visible

        if (act) {
            const float4 zr_m = (z0 > 0)        ? ld4(fb + col + (z0 - 1)   * PLANE) : zero;
            const float4 zr_p = (z0 + CTZ < NZ) ? ld4(fb + col + (z0 + CTZ) * PLANE) : zero;
            const bool lastg = (g == steps - 1);

            float4 zmv = zr_m;                      // rolling old-state z-minus
            #pragma unroll
            for (int k = 0; k < CTZ; ++k) {
                const float4 c  = u[k];
                const float4 zp = (k == CTZ - 1) ? zr_p : u[k + 1];
                float4 ym, yp;
                if (yi > 0) ym = *(const float4*)&sU[k][yi - 1][xq << 2];
                else ym = (y0 > 0)
                        ? ld4(fb + baseb + (z0 + k) * PLANE + (y0 - 1) * NX + (xq << 2))
                        : zero;
                if (yi < CTY - 1) yp = *(const float4*)&sU[k][yi + 1][xq << 2];
                else yp = (y0 + CTY < NY)
                        ? ld4(fb + baseb + (z0 + k) * PLANE + (y0 + CTY) * NX + (xq << 2))
                        : zero;
                float xm = __shfl_up(c.w, 1, 32);   // row-partitioned x exchange
                float xp = __shfl_down(c.x, 1, 32);
                if (xq == 0)  xm = 0.0f;            // x domain boundary
                if (xq == 31) xp = 0.0f;

                float4 o = fkstep(DT, c, xm, xp, ym, yp, zmv, zp,
                                  unpackD(pk[k]), unpackR(pk[k]));
                if (lastg) {
                    float4 oc;
                    oc.x = clip01(o.x); oc.y = clip01(o.y);
                    oc.z = clip01(o.z); oc.w = clip01(o.w);
                    *(float4*)(out + col + (z0 + k) * PLANE) = oc;
                }
                zmv = c;
                u[k] = o;
            }
        }
    }
}

// ===================== fallback: R12 kernel (verified 234us) =====================
__global__ __launch_bounds__(256, 3)
void fk_triple(const float* __restrict__ src, float* __restrict__ dst0,
               float* __restrict__ out, const float* __restrict__ u0,
               const float* __restrict__ Dm, const float* __restrict__ Rm,
               uint32_t* __restrict__ dr, const int* __restrict__ dtd, int p)
{
    const int b  = blockIdx.x >> 9;
    int d = dtd[b]; d = d < 0 ? 0 : (d > 3 ? 3 : d);
    const int steps = d * 10;
    const int g0 = 3 * p;

    const int zb = (blockIdx.x >> 4) & 31;
    const int yt = blockIdx.x & 15;
    const int z0 = zb * TZ, y0 = yt * TY;
    const int tid = threadIdx.x;
    const int xq  = tid & 31;
    const int yi  = tid >> 5;
    const int baseb = b << 21;
    const float4 zero = make_float4(0.f, 0.f, 0.f, 0.f);

    if (g0 >= steps) {
        if (steps == 0 && p == 0) {
            #pragma unroll
            for (int k = 0; k < TZ; ++k) {
                const int idx = baseb + (z0 + k) * PLANE + (y0 + yi) * NX + (xq << 2);
                const float4 v = ld4(u0 + idx);
                float4 o;
                o.x = clip01(v.x); o.y = clip01(v.y);
                o.z = clip01(v.z); o.w = clip01(v.w);
                *(float4*)(out + idx) = o;
            }
        }
        return;
    }
    const bool first = (p == 0);
    const bool last  = (steps - g0 <= 3);
    float* __restrict__ dst = last ? out : dst0;
    const float m1 = (g0 + 1 < steps) ? DT : 0.0f;
    const float m2 = (g0 + 2 < steps) ? DT : 0.0f;

    __shared__ float s1[S1Z * S1Y * NX];
    float* const s2b = s1;

    uint4 pr[TZ];

    {
        const int y = y0 + yi;
        const int colbase = baseb + y * NX + (xq << 2);
        const bool has_ym = (y > 0), has_yp = (y < NY - 1);
        const bool has_l = (xq > 0), has_r = (xq < 31);
        const int zlo = z0 - 2;

        float4 um = ((unsigned)(zlo - 1) < (unsigned)NZ) ? ld4(src + colbase + (zlo - 1) * PLANE) : zero;
        float4 uc = ((unsigned)zlo < (unsigned)NZ) ? ld4(src + colbase + zlo * PLANE) : zero;
        #pragma unroll
        for (int rz = 0; rz < S1Z; ++rz) {
            const int z = zlo + rz;
            const int idx = colbase + z * PLANE;
            const float4 un = ((unsigned)(z + 1) < (unsigned)NZ) ? ld4(src + idx + PLANE) : zero;
            float4 o = zero;
            if ((unsigned)z < (unsigned)NZ) {
                const float4 ym4 = has_ym ? ld4(src + idx - NX) : zero;
                const float4 yp4 = has_yp ? ld4(src + idx + NX) : zero;
                const float xm = has_l ? src[idx - 1] : 0.0f;
                const float xp = has_r ? src[idx + 4] : 0.0f;
                float4 Dv, Rv;
                if (first) {
                    Dv = ld4(Dm + idx);
                    Rv = ld4(Rm + idx);
                    if (rz >= 2 && rz < 2 + TZ) {
                        uint4 pkk;
                        pkk.x = f2bf(Dv.x) | (f2bf(Rv.x) << 16);
                        pkk.y = f2bf(Dv.y) | (f2bf(Rv.y) << 16);
                        pkk.z = f2bf(Dv.z) | (f2bf(Rv.z) << 16);
                        pkk.w = f2bf(Dv.w) | (f2bf(Rv.w) << 16);
                        *(uint4*)(dr + idx) = pkk;
                        pr[rz - 2] = pkk;
                    }
                } else {
                    const uint4 pkk = *(const uint4*)(dr + idx);
                    Dv = unpackD(pkk);
                    Rv = unpackR(pkk);
                    if (rz >= 2 && rz < 2 + TZ) pr[rz - 2] = pkk;
                }
                o = fkstep(DT, uc, xm, xp, ym4, yp4, um, un, Dv, Rv);
            }
            *(float4*)&s1[(rz * S1Y + (yi + 2)) * NX + (xq << 2)] = o;
            um = uc; uc = un;
        }
    }

    for (int i = tid; i < 32 * 32; i += 256) {
        const int cxq = i & 31;
        const int r   = i >> 5;
        const int rr  = r >> 3;
        const int rz  = r & 7;
        const int ry  = (rr < 2) ? rr : rr + 8;
        const int yg = y0 - 2 + ry;
        const int zg = z0 - 2 + rz;
        float4 o = zero;
        if ((unsigned)yg < (unsigned)NY && (unsigned)zg < (unsigned)NZ) {
            const int idx = baseb + zg * PLANE + yg * NX + (cxq << 2);
            const float4 c  = ld4(src + idx);
            const float xm  = (cxq > 0)  ? src[idx - 1] : 0.0f;
            const float xp  = (cxq < 31) ? src[idx + 4] : 0.0f;
            const float4 ym4 = (yg > 0)      ? ld4(src + idx - NX)    : zero;
            const float4 yp4 = (yg < NY - 1) ? ld4(src + idx + NX)    : zero;
            const float4 zm4 = (zg > 0)      ? ld4(src + idx - PLANE) : zero;
            const float4 zp4 = (zg < NZ - 1) ? ld4(src + idx + PLANE) : zero;
            float4 Dv, Rv;
            if (first) {
                Dv = ld4(Dm + idx);
                Rv = ld4(Rm + idx);
            } else {
                const uint4 pkk = *(const uint4*)(dr + idx);
                Dv = unpackD(pkk);
                Rv = unpackR(pkk);
            }
            o = fkstep(DT, c, xm, xp, ym4, yp4, zm4, zp4, Dv, Rv);
        }
        *(float4*)&s1[(rz * S1Y + ry) * NX + (cxq << 2)] = o;
    }
    __syncthreads();

    float4 s2i[S2Z];
    {
        const int ry1 = yi + 2;
        float4 zmv = *(const float4*)&s1[(0 * S1Y + ry1) * NX + (xq << 2)];
        float4 cv  = *(const float4*)&s1[(1 * S1Y + ry1) * NX + (xq << 2)];
        #pragma unroll
        for (int rz2 = 0; rz2 < S2Z; ++rz2) {
            const int rz1 = rz2 + 1;
            const float4 zpv = *(const float4*)&s1[((rz1 + 1) * S1Y + ry1) * NX + (xq << 2)];
            const int z = z0 - 1 + rz2;
            float4 o = zero;
            if ((unsigned)z < (unsigned)NZ) {
                const float* rowc = &s1[(rz1 * S1Y + ry1) * NX];
                const float xm = (xq > 0)  ? rowc[(xq << 2) - 1] : 0.0f;
                const float xp = (xq < 31) ? rowc[(xq << 2) + 4] : 0.0f;
                const float4 ym4 = *(const float4*)&s1[(rz1 * S1Y + ry1 - 1) * NX + (xq << 2)];
                const float4 yp4 = *(const float4*)&s1[(rz1 * S1Y + ry1 + 1) * NX + (xq << 2)];
                float4 Dv, Rv;
                if (rz2 >= 1 && rz2 < 1 + TZ) {
                    Dv = unpackD(pr[rz2 - 1]);
                    Rv = unpackR(pr[rz2 - 1]);
                } else {
                    const int idx = baseb + z * PLANE + (y0 + yi) * NX + (xq << 2);
                    if (first) {
                        Dv = ld4(Dm + idx);
                        Rv = ld4(Rm + idx);
                    } else {
                        const uint4 pkk = *(const uint4*)(dr + idx);
                        Dv = unpackD(pkk);
                        Rv = unpackR(pkk);
                    }
                }
                o = fkstep(m1, cv, xm, xp, ym4, yp4, zmv, zpv, Dv, Rv);
            }
            s2i[rz2] = o;
            zmv = cv; cv = zpv;
        }
    }

    float4 s2h0 = zero, s2h1 = zero;
    #pragma unroll
    for (int kk = 0; kk < 2; ++kk) {
        const int i = tid + kk * 256;
        if (i < 12 * 32) {
            const int cxq = i & 31;
            const int r   = i >> 5;
            const int ry2 = (r < 6) ? 0 : 9;
            const int rz2 = (r < 6) ? r : r - 6;
            const int yg = y0 - 1 + ry2;
            const int zg = z0 - 1 + rz2;
            float4 o = zero;
            if ((unsigned)yg < (unsigned)NY && (unsigned)zg < (unsigned)NZ) {
                const int rz1 = rz2 + 1, ry1 = ry2 + 1;
                const float* rowc = &s1[(rz1 * S1Y + ry1) * NX];
                const float4 cv = *(const float4*)&rowc[cxq << 2];
                const float xm = (cxq > 0)  ? rowc[(cxq << 2) - 1] : 0.0f;
                const float xp = (cxq < 31) ? rowc[(cxq << 2) + 4] : 0.0f;
                const float4 ym4 = *(const float4*)&s1[(rz1 * S1Y + ry1 - 1) * NX + (cxq << 2)];
                const float4 yp4 = *(const float4*)&s1[(rz1 * S1Y + ry1 + 1) * NX + (cxq << 2)];
                const float4 zm4 = *(const float4*)&s1[((rz1 - 1) * S1Y + ry1) * NX + (cxq << 2)];
                const float4 zp4 = *(const float4*)&s1[((rz1 + 1) * S1Y + ry1) * NX + (cxq << 2)];
                float4 Dv, Rv;
                const int idx = baseb + zg * PLANE + yg * NX + (cxq << 2);
                if (first) {
                    Dv = ld4(Dm + idx);
                    Rv = ld4(Rm + idx);
                } else {
                    const uint4 pkk = *(const uint4*)(dr + idx);
                    Dv = unpackD(pkk);
                    Rv = unpackR(pkk);
                }
                o = fkstep(m1, cv, xm, xp, ym4, yp4, zm4, zp4, Dv, Rv);
            }
            if (kk == 0) s2h0 = o; else s2h1 = o;
        }
    }
    __syncthreads();

    {
        const int ry2 = yi + 1;
        #pragma unroll
        for (int rz2 = 0; rz2 < S2Z; ++rz2)
            *(float4*)&s2b[(rz2 * S2Y + ry2) * NX + (xq << 2)] = s2i[rz2];
        #pragma unroll
        for (int kk = 0; kk < 2; ++kk) {
            const int i = tid + kk * 256;
            if (i < 12 * 32) {
                const int cxq = i & 31;
                const int r   = i >> 5;
                const int ry2h = (r < 6) ? 0 : 9;
                const int rz2h = (r < 6) ? r : r - 6;
                *(float4*)&s2b[(rz2h * S2Y + ry2h) * NX + (cxq << 2)] = (kk == 0) ? s2h0 : s2h1;
            }
        }
    }
    __syncthreads();

    {
        const int ry2 = yi + 1;
        const int y   = y0 + yi;
        float4 zmv = *(const float4*)&s2b[(0 * S2Y + ry2) * NX + (xq << 2)];
        float4 cv  = *(const float4*)&s2b[(1 * S2Y + ry2) * NX + (xq << 2)];
        #pragma unroll
        for (int k = 0; k < TZ; ++k) {
            const int rz2 = k + 1;
            const float4 zpv = *(const float4*)&s2b[((rz2 + 1) * S2Y + ry2) * NX + (xq << 2)];
            const float* rowc = &s2b[(rz2 * S2Y + ry2) * NX];
            const float xm = (xq > 0)  ? rowc[(xq << 2) - 1] : 0.0f;
            const float xp = (xq < 31) ? rowc[(xq << 2) + 4] : 0.0f;
            const float4 ym4 = *(const float4*)&s2b[(rz2 * S2Y + ry2 - 1) * NX + (xq << 2)];
            const float4 yp4 = *(const float4*)&s2b[(rz2 * S2Y + ry2 + 1) * NX + (xq << 2)];

            float4 o = fkstep(m2, cv, xm, xp, ym4, yp4, zmv, zpv,
                              unpackD(pr[k]), unpackR(pr[k]));
            if (last) {
                o.x = clip01(o.x); o.y = clip01(o.y);
                o.z = clip01(o.z); o.w = clip01(o.w);
            }
            const int idx = baseb + (z0 + k) * PLANE + y * NX + (xq << 2);
            *(float4*)(dst + idx) = o;
            zmv = cv; cv = zpv;
        }
    }
}

extern "C" void kernel_launch(void* const* d_in, const int* in_sizes, int n_in,
                              void* d_out, int out_size, void* d_ws, size_t ws_size,
                              hipStream_t stream) {
    const float* u0  = (const float*)d_in[0];
    const float* Dm  = (const float*)d_in[1];
    const float* Rm  = (const float*)d_in[2];
    const int*   dtd = (const int*)d_in[3];
    float* out = (float*)d_out;
    float* ws  = (float*)d_ws;
    // ws layout: [0,16M) buf0, [16M,32M) buf1, [32M,48M) packed DR (ws=256MB).
    float* b0 = ws;
    float* b1 = ws + TOTAL;
    uint32_t* dr = (uint32_t*)(ws + 2 * TOTAL);

    void* args[] = { (void*)&u0, (void*)&Dm, (void*)&Rm, (void*)&dtd,
                     (void*)&out, (void*)&b0, (void*)&b1 };
    hipError_t e = hipLaunchCooperativeKernel((const void*)fk_persist,
                                              dim3(CBLOCKS), dim3(CTHREADS),
                                              args, 0, stream);
    if (e != hipSuccess) {
        // Fallback: verified R12 multi-launch path (234us).
        for (int p = 0; p < MAX_TRIPLES; ++p) {
            const float* src = (p == 0) ? u0 : b0 + (((p - 1) & 1) ? TOTAL : 0);
            float* dstb = b0 + ((p & 1) ? TOTAL : 0);
            fk_triple<<<FBLOCKS, 256, 0, stream>>>(src, dstb, out, u0,
                                                   Dm, Rm, dr, dtd, p);
        }
    }
}

// Round 7
// 230.496 us; speedup vs baseline: 4.6181x; 4.6181x over previous
//
#include <hip/hip_runtime.h>
#include <cstdint>

// Fisher-Kolmogorov explicit Euler, B=2, 128^3, up to 30 masked micro-steps
// (delta_t_days = randint(0,4) -> d <= 3 -> steps <= 30).
// Round-16: R12 (best verified, 234us) + XCD-SLAB BLOCK SWIZZLE (single var).
//  Evidence so far: byte cuts don't pay (R14), occupancy null (R10=R12!=R11),
//  barriers 2 vs 3 equal, grid.sync costs ~33us (R15 -> persistent dead).
//  R14 counters (VALUBusy 9-20%, Occ 20%, 2.3TB/s eff) -> L2-miss LATENCY
//  bound: ping-pong buffers are re-read next launch by blocks scattered
//  across 8 non-coherent L2s -> L3 round-trips (~600-900cy) that 12 waves/CU
//  can't hide.
//  Fix: blockIdx mapped so bid%8 (XCD round-robin key) = contiguous z-slab:
//    slab = bid&7 owns z-tiles [4*slab, 4*slab+4) x all y x both batches.
//  Same tile -> same XCD every launch (ping-pong L2 reuse); y-halos in-slab;
//  z-halo crossings only at 8 slab boundaries.
//  Everything else is byte-identical to R12.

constexpr int NX = 128, NY = 128, NZ = 128;
constexpr int PLANE = NX * NY;            // 16384
constexpr int VOL   = NZ * PLANE;         // 2,097,152
constexpr int TOTAL = 2 * VOL;            // 4,194,304
constexpr float DT  = 0.1f;               // MICRO_DT
constexpr int MAX_TRIPLES = 10;           // 30 steps / 3

constexpr int TY = 8, TZ = 4;             // block interior tile (x full 128)
constexpr int S1Z = TZ + 4, S1Y = TY + 4; // step-1 region: 8 z x 12 y (48 KB)
constexpr int S2Z = TZ + 2, S2Y = TY + 2; // step-2 region: 6 z x 10 y (aliased)
constexpr int BLOCKS = 2 * (NZ / TZ) * (NY / TY);  // 2*32*16 = 1024

__device__ __forceinline__ float4 ld4(const float* p) { return *(const float4*)p; }

__device__ __forceinline__ uint32_t f2bf(float f) {
    uint32_t u = __float_as_uint(f);
    u += 0x7fffu + ((u >> 16) & 1u);      // round-to-nearest-even
    return u >> 16;
}
__device__ __forceinline__ float bf_lo(uint32_t p) { return __uint_as_float(p << 16); }
__device__ __forceinline__ float bf_hi(uint32_t p) { return __uint_as_float(p & 0xffff0000u); }
__device__ __forceinline__ float clip01(float v) { return fminf(fmaxf(v, 0.0f), 1.0f); }

__device__ __forceinline__ float4 fkstep(float dt, float4 c, float xm, float xp,
                                         float4 ym, float4 yp,
                                         float4 zm, float4 zp,
                                         float4 Dv, float4 Rv) {
    float4 o;
    o.x = fmaf(dt, fmaf(Dv.x, (xm + c.y) + (ym.x + yp.x) + (zm.x + zp.x) - 6.0f * c.x,
                        Rv.x * c.x * (1.0f - c.x)), c.x);
    o.y = fmaf(dt, fmaf(Dv.y, (c.x + c.z) + (ym.y + yp.y) + (zm.y + zp.y) - 6.0f * c.y,
                        Rv.y * c.y * (1.0f - c.y)), c.y);
    o.z = fmaf(dt, fmaf(Dv.z, (c.y + c.w) + (ym.z + yp.z) + (zm.z + zp.z) - 6.0f * c.z,
                        Rv.z * c.z * (1.0f - c.z)), c.z);
    o.w = fmaf(dt, fmaf(Dv.w, (c.z + xp) + (ym.w + yp.w) + (zm.w + zp.w) - 6.0f * c.w,
                        Rv.w * c.w * (1.0f - c.w)), c.w);
    return o;
}

__device__ __forceinline__ float4 unpackD(uint4 p) {
    return make_float4(bf_lo(p.x), bf_lo(p.y), bf_lo(p.z), bf_lo(p.w));
}
__device__ __forceinline__ float4 unpackR(uint4 p) {
    return make_float4(bf_hi(p.x), bf_hi(p.y), bf_hi(p.z), bf_hi(p.w));
}

__global__ __launch_bounds__(256, 3)
void fk_triple(const float* __restrict__ src, float* __restrict__ dst0,
               float* __restrict__ out, const float* __restrict__ u0,
               const float* __restrict__ Dm, const float* __restrict__ Rm,
               uint32_t* __restrict__ dr, const int* __restrict__ dtd, int p)
{
    // ---- XCD-slab swizzle: bid%8 selects a contiguous z-slab ----
    const int bid  = blockIdx.x;
    const int slab = bid & 7;                        // XCD key 0..7
    const int rest = bid >> 3;                       // 0..127
    const int b    = rest >> 6;                      // batch item
    const int zw   = (rest >> 4) & 3;                // z tile within slab
    const int yt   = rest & 15;                      // y tile
    const int zb   = slab * 4 + zw;                  // z tile 0..31

    int d = dtd[b]; d = d < 0 ? 0 : (d > 3 ? 3 : d); // randint(0,4) is excl-upper
    const int steps = d * 10;
    const int g0 = 3 * p;                            // first global step of launch

    const int z0 = zb * TZ, y0 = yt * TY;
    const int tid = threadIdx.x;
    const int xq  = tid & 31;                        // float4 lane within row
    const int yi  = tid >> 5;                        // 0..7
    const int baseb = b << 21;
    const float4 zero = make_float4(0.f, 0.f, 0.f, 0.f);

    if (g0 >= steps) {
        // d==0 items never get a step write: emit clip(u0) once, in launch 0.
        if (steps == 0 && p == 0) {
            #pragma unroll
            for (int k = 0; k < TZ; ++k) {
                const int idx = baseb + (z0 + k) * PLANE + (y0 + yi) * NX + (xq << 2);
                const float4 v = ld4(u0 + idx);
                float4 o;
                o.x = clip01(v.x); o.y = clip01(v.y);
                o.z = clip01(v.z); o.w = clip01(v.w);
                *(float4*)(out + idx) = o;
            }
        }
        return;                                      // block-uniform exit
    }
    const bool first = (p == 0);
    const bool last  = (steps - g0 <= 3);
    float* __restrict__ dst = last ? out : dst0;
    const float m1 = (g0 + 1 < steps) ? DT : 0.0f;   // sub-step masks (g0 active)
    const float m2 = (g0 + 2 < steps) ? DT : 0.0f;   // fmaf(0,du,u)==u exactly

    __shared__ float s1[S1Z * S1Y * NX];             // 48 KiB; s2 aliases this
    float* const s2b = s1;                           // s2 layout: [S2Z][S2Y][NX]

    uint4 pr[TZ];                                    // packed (D,rho) bf16, interior

    // ---- Phase 1 pass 0: step-1 on interior-y columns of s1, z-rolled over
    // all 8 s1 planes (z0-2 .. z0+5). Captures/publishes interior dr. ----
    {
        const int y = y0 + yi;                       // in-domain by construction
        const int colbase = baseb + y * NX + (xq << 2);
        const bool has_ym = (y > 0), has_yp = (y < NY - 1);
        const bool has_l = (xq > 0), has_r = (xq < 31);
        const int zlo = z0 - 2;

        float4 um = ((unsigned)(zlo - 1) < (unsigned)NZ) ? ld4(src + colbase + (zlo - 1) * PLANE) : zero;
        float4 uc = ((unsigned)zlo < (unsigned)NZ) ? ld4(src + colbase + zlo * PLANE) : zero;
        #pragma unroll
        for (int rz = 0; rz < S1Z; ++rz) {
            const int z = zlo + rz;
            const int idx = colbase + z * PLANE;
            const float4 un = ((unsigned)(z + 1) < (unsigned)NZ) ? ld4(src + idx + PLANE) : zero;
            float4 o = zero;
            if ((unsigned)z < (unsigned)NZ) {
                const float4 ym4 = has_ym ? ld4(src + idx - NX) : zero;
                const float4 yp4 = has_yp ? ld4(src + idx + NX) : zero;
                const float xm = has_l ? src[idx - 1] : 0.0f;
                const float xp = has_r ? src[idx + 4] : 0.0f;
                float4 Dv, Rv;
                if (first) {
                    Dv = ld4(Dm + idx);
                    Rv = ld4(Rm + idx);
                    if (rz >= 2 && rz < 2 + TZ) {    // interior z: publish + keep
                        uint4 pk;
                        pk.x = f2bf(Dv.x) | (f2bf(Rv.x) << 16);
                        pk.y = f2bf(Dv.y) | (f2bf(Rv.y) << 16);
                        pk.z = f2bf(Dv.z) | (f2bf(Rv.z) << 16);
                        pk.w = f2bf(Dv.w) | (f2bf(Rv.w) << 16);
                        *(uint4*)(dr + idx) = pk;
                        pr[rz - 2] = pk;
                    }
                } else {
                    const uint4 pk = *(const uint4*)(dr + idx);
                    Dv = unpackD(pk);
                    Rv = unpackR(pk);
                    if (rz >= 2 && rz < 2 + TZ) pr[rz - 2] = pk;
                }
                o = fkstep(DT, uc, xm, xp, ym4, yp4, um, un, Dv, Rv);
            }
            *(float4*)&s1[(rz * S1Y + (yi + 2)) * NX + (xq << 2)] = o;
            um = uc; uc = un;
        }
    }

    // ---- Phase 1 pass 1: step-1 on the 4 y-halo rows x 8 planes (32 row-
    // tasks, flat over all threads, 4 iterations). ----
    for (int i = tid; i < 32 * 32; i += 256) {
        const int cxq = i & 31;
        const int r   = i >> 5;                      // 0..31
        const int rr  = r >> 3;                      // 0..3
        const int rz  = r & 7;
        const int ry  = (rr < 2) ? rr : rr + 8;      // 0,1,10,11
        const int y = y0 - 2 + ry;
        const int z = z0 - 2 + rz;
        float4 o = zero;                             // out-of-domain -> 0
        if ((unsigned)y < (unsigned)NY && (unsigned)z < (unsigned)NZ) {
            const int idx = baseb + z * PLANE + y * NX + (cxq << 2);
            const float4 c  = ld4(src + idx);
            const float xm  = (cxq > 0)  ? src[idx - 1] : 0.0f;
            const float xp  = (cxq < 31) ? src[idx + 4] : 0.0f;
            const float4 ym4 = (y > 0)      ? ld4(src + idx - NX)    : zero;
            const float4 yp4 = (y < NY - 1) ? ld4(src + idx + NX)    : zero;
            const float4 zm4 = (z > 0)      ? ld4(src + idx - PLANE) : zero;
            const float4 zp4 = (z < NZ - 1) ? ld4(src + idx + PLANE) : zero;
            float4 Dv, Rv;
            if (first) {
                Dv = ld4(Dm + idx);
                Rv = ld4(Rm + idx);
            } else {
                const uint4 pk = *(const uint4*)(dr + idx);
                Dv = unpackD(pk);
                Rv = unpackR(pk);
            }
            o = fkstep(DT, c, xm, xp, ym4, yp4, zm4, zp4, Dv, Rv);
        }
        *(float4*)&s1[(rz * S1Y + ry) * NX + (cxq << 2)] = o;
    }
    __syncthreads();                                 // barrier 1: s1 complete

    // ---- Phase 2 (register-staged): step-2 from s1 into registers ----
    float4 s2i[S2Z];                                 // interior rows, ry2 = yi+1
    {
        const int ry1 = yi + 2;                      // this cell's s1 row
        float4 zmv = *(const float4*)&s1[(0 * S1Y + ry1) * NX + (xq << 2)];
        float4 cv  = *(const float4*)&s1[(1 * S1Y + ry1) * NX + (xq << 2)];
        #pragma unroll
        for (int rz2 = 0; rz2 < S2Z; ++rz2) {
            const int rz1 = rz2 + 1;
            const float4 zpv = *(const float4*)&s1[((rz1 + 1) * S1Y + ry1) * NX + (xq << 2)];
            const int z = z0 - 1 + rz2;
            float4 o = zero;
            if ((unsigned)z < (unsigned)NZ) {
                const float* rowc = &s1[(rz1 * S1Y + ry1) * NX];
                const float xm = (xq > 0)  ? rowc[(xq << 2) - 1] : 0.0f;
                const float xp = (xq < 31) ? rowc[(xq << 2) + 4] : 0.0f;
                const float4 ym4 = *(const float4*)&s1[(rz1 * S1Y + ry1 - 1) * NX + (xq << 2)];
                const float4 yp4 = *(const float4*)&s1[(rz1 * S1Y + ry1 + 1) * NX + (xq << 2)];
                float4 Dv, Rv;
                if (rz2 >= 1 && rz2 < 1 + TZ) {      // interior z: from registers
                    Dv = unpackD(pr[rz2 - 1]);
                    Rv = unpackR(pr[rz2 - 1]);
                } else {                             // z halo planes
                    const int idx = baseb + z * PLANE + (y0 + yi) * NX + (xq << 2);
                    if (first) {
                        Dv = ld4(Dm + idx);
                        Rv = ld4(Rm + idx);
                    } else {
                        const uint4 pk = *(const uint4*)(dr + idx);
                        Dv = unpackD(pk);
                        Rv = unpackR(pk);
                    }
                }
                o = fkstep(m1, cv, xm, xp, ym4, yp4, zmv, zpv, Dv, Rv);
            }
            s2i[rz2] = o;
            zmv = cv; cv = zpv;
        }
    }

    // y-halo rows of s2: 12 row-tasks x 32 f4 = 384 tasks, staged in regs.
    float4 s2h0 = zero, s2h1 = zero;
    #pragma unroll
    for (int kk = 0; kk < 2; ++kk) {
        const int i = tid + kk * 256;
        if (i < 12 * 32) {
            const int cxq = i & 31;
            const int r   = i >> 5;                  // 0..11
            const int ry2 = (r < 6) ? 0 : 9;
            const int rz2 = (r < 6) ? r : r - 6;
            const int y = y0 - 1 + ry2;
            const int z = z0 - 1 + rz2;
            float4 o = zero;
            if ((unsigned)y < (unsigned)NY && (unsigned)z < (unsigned)NZ) {
                const int rz1 = rz2 + 1, ry1 = ry2 + 1;
                const float* rowc = &s1[(rz1 * S1Y + ry1) * NX];
                const float4 cv = *(const float4*)&rowc[cxq << 2];
                const float xm = (cxq > 0)  ? rowc[(cxq << 2) - 1] : 0.0f;
                const float xp = (cxq < 31) ? rowc[(cxq << 2) + 4] : 0.0f;
                const float4 ym4 = *(const float4*)&s1[(rz1 * S1Y + ry1 - 1) * NX + (cxq << 2)];
                const float4 yp4 = *(const float4*)&s1[(rz1 * S1Y + ry1 + 1) * NX + (cxq << 2)];
                const float4 zm4 = *(const float4*)&s1[((rz1 - 1) * S1Y + ry1) * NX + (cxq << 2)];
                const float4 zp4 = *(const float4*)&s1[((rz1 + 1) * S1Y + ry1) * NX + (cxq << 2)];
                float4 Dv, Rv;
                const int idx = baseb + z * PLANE + y * NX + (cxq << 2);
                if (first) {
                    Dv = ld4(Dm + idx);
                    Rv = ld4(Rm + idx);
                } else {
                    const uint4 pk = *(const uint4*)(dr + idx);
                    Dv = unpackD(pk);
                    Rv = unpackR(pk);
                }
                o = fkstep(m1, cv, xm, xp, ym4, yp4, zm4, zp4, Dv, Rv);
            }
            if (kk == 0) s2h0 = o; else s2h1 = o;
        }
    }
    __syncthreads();                                 // barrier 2: s1 reads done

    // ---- Publish staged s2 into the same storage (s2 layout) ----
    {
        const int ry2 = yi + 1;
        #pragma unroll
        for (int rz2 = 0; rz2 < S2Z; ++rz2)
            *(float4*)&s2b[(rz2 * S2Y + ry2) * NX + (xq << 2)] = s2i[rz2];
        #pragma unroll
        for (int kk = 0; kk < 2; ++kk) {
            const int i = tid + kk * 256;
            if (i < 12 * 32) {
                const int cxq = i & 31;
                const int r   = i >> 5;
                const int ry2h = (r < 6) ? 0 : 9;
                const int rz2h = (r < 6) ? r : r - 6;
                *(float4*)&s2b[(rz2h * S2Y + ry2h) * NX + (cxq << 2)] = (kk == 0) ? s2h0 : s2h1;
            }
        }
    }
    __syncthreads();                                 // barrier 3: s2 complete

    // ---- Phase 3: step-3 on the interior from s2; dr from registers;
    // z-rolled s2 planes; clip + redirect to `out` on the item's last launch. ----
    {
        const int ry2 = yi + 1;
        const int y   = y0 + yi;
        float4 zmv = *(const float4*)&s2b[(0 * S2Y + ry2) * NX + (xq << 2)];
        float4 cv  = *(const float4*)&s2b[(1 * S2Y + ry2) * NX + (xq << 2)];
        #pragma unroll
        for (int k = 0; k < TZ; ++k) {
            const int rz2 = k + 1;
            const float4 zpv = *(const float4*)&s2b[((rz2 + 1) * S2Y + ry2) * NX + (xq << 2)];
            const float* rowc = &s2b[(rz2 * S2Y + ry2) * NX];
            const float xm = (xq > 0)  ? rowc[(xq << 2) - 1] : 0.0f;
            const float xp = (xq < 31) ? rowc[(xq << 2) + 4] : 0.0f;
            const float4 ym4 = *(const float4*)&s2b[(rz2 * S2Y + ry2 - 1) * NX + (xq << 2)];
            const float4 yp4 = *(const float4*)&s2b[(rz2 * S2Y + ry2 + 1) * NX + (xq << 2)];

            float4 o = fkstep(m2, cv, xm, xp, ym4, yp4, zmv, zpv,
                              unpackD(pr[k]), unpackR(pr[k]));
            if (last) {
                o.x = clip01(o.x); o.y = clip01(o.y);
                o.z = clip01(o.z); o.w = clip01(o.w);
            }
            const int idx = baseb + (z0 + k) * PLANE + y * NX + (xq << 2);
            *(float4*)(dst + idx) = o;
            zmv = cv; cv = zpv;
        }
    }
}

extern "C" void kernel_launch(void* const* d_in, const int* in_sizes, int n_in,
                              void* d_out, int out_size, void* d_ws, size_t ws_size,
                              hipStream_t stream) {
    const float* u0  = (const float*)d_in[0];
    const float* Dm  = (const float*)d_in[1];
    const float* Rm  = (const float*)d_in[2];
    const int*   dtd = (const int*)d_in[3];
    float* out = (float*)d_out;
    float* ws  = (float*)d_ws;
    // ws layout: [0,16M) buf0, [16M,32M) buf1, [32M,48M) packed DR (ws=256MB).
    float* buf[2] = { ws, ws + TOTAL };
    uint32_t* dr = (uint32_t*)(ws + 2 * TOTAL);

    // Launch p advances steps 3p..3p+2 (inactive sub-steps masked to identity).
    // src: u0 for p=0 else buf[(p-1)&1]; normal dst alternates buf[p&1]; an
    // item's LAST launch redirects to `out` (clipped) on-device. d==0 items
    // emit clip(u0) during launch 0.
    for (int p = 0; p < MAX_TRIPLES; ++p) {
        const float* src = (p == 0) ? u0 : buf[(p - 1) & 1];
        fk_triple<<<BLOCKS, 256, 0, stream>>>(src, buf[p & 1], out, u0,
                                              Dm, Rm, dr, dtd, p);
    }
}